// Round 1
// baseline (1643.534 us; speedup 1.0000x reference)
//
#include <hip/hip_runtime.h>
#include <stdint.h>

#define VOCAB 128000
#define DIM   2048
#define MTOT  16384   // BATCH*SEQ = 4*4096
#define KDIM  2048
#define NDIM  2048

#define BM 128
#define BN 128
#define BK 32

using f32x4  = __attribute__((ext_vector_type(4))) float;
using bf16x8 = __attribute__((ext_vector_type(8))) short;   // 8 bf16 in 4 VGPRs (guide §3)
using s16x4  = __attribute__((ext_vector_type(4))) short;

__device__ __forceinline__ unsigned short f2bf_rne(float x) {
    unsigned int u = __float_as_uint(x);
    u += 0x7fffu + ((u >> 16) & 1u);
    return (unsigned short)(u >> 16);
}
__device__ __forceinline__ float bf2f(unsigned short h) {
    return __uint_as_float(((unsigned int)h) << 16);
}

__device__ __forceinline__ void gload16(const void* g, void* l) {
    __builtin_amdgcn_global_load_lds(
        (const __attribute__((address_space(1))) unsigned int*)g,
        (__attribute__((address_space(3))) unsigned int*)l,
        16, 0, 0);
}

// ---------------------------------------------------------------------------
// Kernel 1: rot [K][N] f32  ->  Bt_hi/Bt_lo [N][K] bf16 (hi + residual lo)
// 64x64 tiles via LDS transpose; both global read and write coalesced.
// ---------------------------------------------------------------------------
__global__ __launch_bounds__(256) void convert_rot(
    const float* __restrict__ rot,
    unsigned short* __restrict__ bt_hi,
    unsigned short* __restrict__ bt_lo)
{
    __shared__ float tile[64][65];   // +1 pad: conflict-free transpose read
    const int t  = threadIdx.x;
    const int n0 = blockIdx.x * 64;
    const int k0 = blockIdx.y * 64;
    const int rsub = t >> 6;         // 0..3
    const int c    = t & 63;         // 0..63

#pragma unroll
    for (int it = 0; it < 16; ++it) {
        int r = it * 4 + rsub;                       // k-local
        tile[r][c] = rot[(size_t)(k0 + r) * NDIM + n0 + c];
    }
    __syncthreads();
#pragma unroll
    for (int it = 0; it < 16; ++it) {
        int nl = it * 4 + rsub;                      // n-local
        float v = tile[c][nl];                       // c = k-local (stride-65 => no conflicts)
        unsigned short hi = f2bf_rne(v);
        unsigned short lo = f2bf_rne(v - bf2f(hi));
        size_t o = (size_t)(n0 + nl) * KDIM + k0 + c;
        bt_hi[o] = hi;
        bt_lo[o] = lo;
    }
}

// ---------------------------------------------------------------------------
// Kernel 2: gathered split-bf16 GEMM
//   out[m][n] = sum_k W[ids[m]][k] * rot[k][n]
//   C = Ah*Bh + Ah*Bl + Al*Bh  (3 MFMA passes, fp32 accumulate)
// 128x128 tile, BK=32, 4 waves of 64x64, mfma_f32_16x16x32_bf16.
// LDS layout per operand: [frag(8)][kchunk(4)][rc(16)][8 bf16]
//   -> fragment ds_read_b128 is linear in lane id (conflict-free).
// ---------------------------------------------------------------------------
__global__ __launch_bounds__(256) void rot_embed_gemm(
    const int*            __restrict__ ids,
    const float*          __restrict__ W,
    const unsigned short* __restrict__ bt_hi,
    const unsigned short* __restrict__ bt_lo,
    float*                __restrict__ out)
{
    __shared__ unsigned short sA_hi[8 * 4 * 16 * 8];  // 8 KB
    __shared__ unsigned short sA_lo[8 * 4 * 16 * 8];
    __shared__ unsigned short sB_hi[8 * 4 * 16 * 8];
    __shared__ unsigned short sB_lo[8 * 4 * 16 * 8];
    __shared__ int sIds[BM];

    const int t  = threadIdx.x;
    const int bn = blockIdx.x * BN;
    const int bm = blockIdx.y * BM;

    if (t < BM) sIds[t] = ids[bm + t];
    __syncthreads();

    const int l  = t & 63;
    const int w  = t >> 6;
    const int wr = w >> 1;   // wave row (0..1)
    const int wc = w & 1;    // wave col (0..1)

    // --- A staging map: thread t loads rows r+32*rr, cols [c4, c4+4) each K-step
    const int r  = t >> 3;           // 0..31
    const int c4 = (t & 7) * 4;      // 0,4,...,28
    size_t arow[4];
    int    aoff[4];
#pragma unroll
    for (int rr = 0; rr < 4; ++rr) {
        int row = r + rr * 32;
        arow[rr] = (size_t)sIds[row] * DIM;
        aoff[rr] = (row >> 4) * 512 + (c4 >> 3) * 128 + (row & 15) * 8 + (c4 & 7);
    }

    // --- B staging map (global_load_lds: wave-uniform LDS base + lane*16)
    int bbase[2], bnfrag[2], bkch[2], bcol[2];
#pragma unroll
    for (int i = 0; i < 2; ++i) {
        int basec = w * 128 + i * 64;        // wave-uniform chunk base
        int q     = basec + l;               // this lane's chunk
        bbase[i]  = basec * 8;               // ushort offset of wave base
        bnfrag[i] = q >> 6;
        bkch[i]   = (q >> 4) & 3;
        bcol[i]   = q & 15;
    }

    f32x4 acc[4][4];
#pragma unroll
    for (int m = 0; m < 4; ++m)
#pragma unroll
        for (int n = 0; n < 4; ++n)
            acc[m][n] = (f32x4){0.f, 0.f, 0.f, 0.f};

    const int afo = (l >> 4) * 128 + (l & 15) * 8;   // fragment read offset within a frag-block

    for (int kt = 0; kt < KDIM / BK; ++kt) {
        const int k0 = kt * BK;

        // ---- stage A: gather fp32, split to bf16 hi/lo, ds_write
#pragma unroll
        for (int rr = 0; rr < 4; ++rr) {
            f32x4 v = *(const f32x4*)(W + arow[rr] + k0 + c4);
            s16x4 hi, lo;
#pragma unroll
            for (int i = 0; i < 4; ++i) {
                unsigned short h = f2bf_rne(v[i]);
                hi[i] = (short)h;
                lo[i] = (short)f2bf_rne(v[i] - bf2f(h));
            }
            *(s16x4*)(sA_hi + aoff[rr]) = hi;
            *(s16x4*)(sA_lo + aoff[rr]) = lo;
        }

        // ---- stage B: async global->LDS, width 16
#pragma unroll
        for (int i = 0; i < 2; ++i) {
            size_t go = (size_t)(bn + bnfrag[i] * 16 + bcol[i]) * KDIM + k0 + bkch[i] * 8;
            gload16(bt_hi + go, sB_hi + bbase[i]);
            gload16(bt_lo + go, sB_lo + bbase[i]);
        }

        __syncthreads();   // drains vmcnt(0) before barrier (compiler-enforced)

        // ---- fragments (linear-in-lane ds_read_b128)
        bf16x8 ah[4], al[4], bh[4], bl[4];
#pragma unroll
        for (int m = 0; m < 4; ++m) {
            ah[m] = *(const bf16x8*)(sA_hi + (wr * 4 + m) * 512 + afo);
            al[m] = *(const bf16x8*)(sA_lo + (wr * 4 + m) * 512 + afo);
        }
#pragma unroll
        for (int n = 0; n < 4; ++n) {
            bh[n] = *(const bf16x8*)(sB_hi + (wc * 4 + n) * 512 + afo);
            bl[n] = *(const bf16x8*)(sB_lo + (wc * 4 + n) * 512 + afo);
        }

        // ---- 48 MFMAs: hi*hi + hi*lo + lo*hi
#pragma unroll
        for (int m = 0; m < 4; ++m)
#pragma unroll
            for (int n = 0; n < 4; ++n) {
                acc[m][n] = __builtin_amdgcn_mfma_f32_16x16x32_bf16(ah[m], bh[n], acc[m][n], 0, 0, 0);
                acc[m][n] = __builtin_amdgcn_mfma_f32_16x16x32_bf16(ah[m], bl[n], acc[m][n], 0, 0, 0);
                acc[m][n] = __builtin_amdgcn_mfma_f32_16x16x32_bf16(al[m], bh[n], acc[m][n], 0, 0, 0);
            }

        __syncthreads();
    }

    // ---- epilogue: C/D mapping col=lane&15, row=(lane>>4)*4+j (m89-verified)
#pragma unroll
    for (int m = 0; m < 4; ++m) {
        int row0 = bm + wr * 64 + m * 16 + (l >> 4) * 4;
#pragma unroll
        for (int n = 0; n < 4; ++n) {
            int col = bn + wc * 64 + n * 16 + (l & 15);
#pragma unroll
            for (int j = 0; j < 4; ++j)
                out[(size_t)(row0 + j) * NDIM + col] = acc[m][n][j];
        }
    }
}

// ---------------------------------------------------------------------------
extern "C" void kernel_launch(void* const* d_in, const int* in_sizes, int n_in,
                              void* d_out, int out_size, void* d_ws, size_t ws_size,
                              hipStream_t stream)
{
    const int*   ids = (const int*)d_in[0];
    const float* W   = (const float*)d_in[1];
    const float* rot = (const float*)d_in[2];
    float*       out = (float*)d_out;

    unsigned short* bt_hi = (unsigned short*)d_ws;                      // 8 MB
    unsigned short* bt_lo = bt_hi + (size_t)NDIM * KDIM;                // 8 MB

    convert_rot<<<dim3(NDIM / 64, KDIM / 64), 256, 0, stream>>>(rot, bt_hi, bt_lo);
    rot_embed_gemm<<<dim3(NDIM / BN, MTOT / BM), 256, 0, stream>>>(ids, W, bt_hi, bt_lo, out);
}